// Round 11
// baseline (37849.869 us; speedup 1.0000x reference)
//
#include <hip/hip_runtime.h>

// VanillaRNN — bit-exact specialized kernel, R11: row+panel split (4 waves/SIMD).
// Reference arithmetic (oracle winner v=75, verified bit-exact full-batch R6):
//   GEMM: per column, TWO k-panels {0..511},{512..1023}; each an independent
//         ascending-k FMA chain from 0; G = s0 + s1 (single commutative add).
//   z    = fma(x_t, w_c, G) + b_c
//   tanh = XLA FastTanh FMA-Horner, clamp ±7.99881172180175781, |x|<4e-4 -> x,
//          IEEE f32 divide.
// DO NOT reorder any FP op in the recurrence.
//
// R11 parallelism: thread = (rowgroup rg, panel pp, colgroup c0).
//   - 8 batch rows -> 2 rowgroups x 4 rows (rows are independent dot products;
//     no FP chain touched).
//   - 2 panels as in R10; pp=1 publishes subtotals via LDS, pp=0 combines+tanh.
//   - 256 blocks x 1024 threads = 16 waves/CU = 4/SIMD (R10 was 2/SIMD,
//     VALUBusy 69%; more waves hide L2/LDS/barrier latency).
// Floors: FMA issue 14 ms; W_hh L2 traffic 512 GB ~ 15 ms at 34.5 TB/s.

#define SEQ   512
#define HID   1024
#define NCLS  10
#define TPB   1024
#define ROWS  8
#define RPT   4               // rows per thread (= ROWS/2 rowgroups)
#define CLAMPV 7.99881172180175781f

__device__ __forceinline__ float tanh_win(float x) {
#pragma clang fp contract(off)
    float xc = fminf(fmaxf(x, -CLAMPV), CLAMPV);
    float x2 = xc * xc;
    float p = -2.76076847742355e-16f;
    p = __fmaf_rn(x2, p,  2.00018790482477e-13f);
    p = __fmaf_rn(x2, p, -8.60467152213735e-11f);
    p = __fmaf_rn(x2, p,  5.12229709037114e-08f);
    p = __fmaf_rn(x2, p,  1.48572235717979e-05f);
    p = __fmaf_rn(x2, p,  6.37261928875436e-04f);
    p = __fmaf_rn(x2, p,  4.89352455891786e-03f);
    p = xc * p;
    float q = 1.19825839466702e-06f;
    q = __fmaf_rn(x2, q,  1.18534705686654e-04f);
    q = __fmaf_rn(x2, q,  2.26843463243900e-03f);
    q = __fmaf_rn(x2, q,  4.89352518554385e-03f);
    float r = p / q;                      // IEEE f32 divide
    return (fabsf(x) < 0.0004f) ? x : r;  // passthrough on unclamped x
}

#define MAC4(hv, wv)                              \
    sv.x = __fmaf_rn((hv), (wv).x, sv.x);         \
    sv.y = __fmaf_rn((hv), (wv).y, sv.y);         \
    sv.z = __fmaf_rn((hv), (wv).z, sv.z);         \
    sv.w = __fmaf_rn((hv), (wv).w, sv.w);

// One 512-long k-panel over RPT rows: independent FMA chain per (row, col)
// from zero — FP sequence per chain identical to R9/R10 (bit-exact).
__device__ __forceinline__ void panel512(float4 s[RPT],
                                         const float* __restrict__ hrows,
                                         const float* __restrict__ Whh,
                                         int ks, int c0) {
#pragma clang fp contract(off)
    #pragma unroll
    for (int r = 0; r < RPT; ++r) s[r] = float4{0.f, 0.f, 0.f, 0.f};

    unsigned off = (unsigned)(ks * HID + c0);
    #pragma unroll 2
    for (int j = ks; j < ks + 512; j += 8) {
        const float4 w0 = *reinterpret_cast<const float4*>(Whh + off);
        const float4 w1 = *reinterpret_cast<const float4*>(Whh + off + 1u * HID);
        const float4 w2 = *reinterpret_cast<const float4*>(Whh + off + 2u * HID);
        const float4 w3 = *reinterpret_cast<const float4*>(Whh + off + 3u * HID);
        const float4 w4 = *reinterpret_cast<const float4*>(Whh + off + 4u * HID);
        const float4 w5 = *reinterpret_cast<const float4*>(Whh + off + 5u * HID);
        const float4 w6 = *reinterpret_cast<const float4*>(Whh + off + 6u * HID);
        const float4 w7 = *reinterpret_cast<const float4*>(Whh + off + 7u * HID);
        off += 8u * HID;
        #pragma unroll
        for (int r = 0; r < RPT; ++r) {
            const float4 ha = *reinterpret_cast<const float4*>(&hrows[r * HID + j]);
            const float4 hb = *reinterpret_cast<const float4*>(&hrows[r * HID + j + 4]);
            float4 sv = s[r];
            MAC4(ha.x, w0); MAC4(ha.y, w1); MAC4(ha.z, w2); MAC4(ha.w, w3);
            MAC4(hb.x, w4); MAC4(hb.y, w5); MAC4(hb.z, w6); MAC4(hb.w, w7);
            s[r] = sv;
        }
    }
}

__launch_bounds__(TPB, 4)
__global__ void rnn_win(const float* __restrict__ x, const float* __restrict__ W_hx,
                        const float* __restrict__ Whh, const float* __restrict__ W_ph,
                        const float* __restrict__ bh, const float* __restrict__ bp,
                        float* __restrict__ out) {
#pragma clang fp contract(off)
    __shared__ float hl[ROWS * HID];   // 32 KB  current hidden state
    __shared__ float xl[ROWS * SEQ];   // 16 KB  staged inputs
    __shared__ float sb[ROWS * HID];   // 32 KB  panel-1 subtotal exchange
    const int tid  = threadIdx.x;
    const int blk  = blockIdx.x;
    const int col  = tid & 255;        // colgroup id
    const int pp   = (tid >> 8) & 1;   // panel id: 0 -> k 0..511, 1 -> k 512..1023
    const int rg   = tid >> 9;         // rowgroup id: rows rg*4 .. rg*4+3
    const int c0   = col * 4;
    const int row0 = blk * ROWS;

    for (int i = tid; i < ROWS * SEQ; i += TPB) xl[i] = x[(size_t)row0 * SEQ + i];
    for (int i = tid; i < ROWS * HID; i += TPB) hl[i] = 0.0f;

    const float4 w4 = *reinterpret_cast<const float4*>(W_hx + c0);
    const float4 b4 = *reinterpret_cast<const float4*>(bh + c0);
    const float* hrows = hl + rg * RPT * HID;       // this thread's 4 rows
    float* sbrows      = sb + rg * RPT * HID;
    __syncthreads();

    for (int t = 0; t < SEQ; ++t) {
        float4 s[RPT];
        panel512(s, hrows, Whh, pp * 512, c0);

        if (pp == 1) {
            #pragma unroll
            for (int r = 0; r < RPT; ++r)
                *reinterpret_cast<float4*>(&sbrows[r * HID + c0]) = s[r];
        }
        __syncthreads();   // h_t reads done; sb (s1) visible

        if (pp == 0) {
            #pragma unroll
            for (int r = 0; r < RPT; ++r) {
                const float4 s1 = *reinterpret_cast<const float4*>(&sbrows[r * HID + c0]);
                const float xv = xl[(rg * RPT + r) * SEQ + t];
                float4 g;
                g.x = s[r].x + s1.x;   // = R9's s0 + s1 (same rounding)
                g.y = s[r].y + s1.y;
                g.z = s[r].z + s1.z;
                g.w = s[r].w + s1.w;
                float4 hn;
                hn.x = tanh_win(__fmaf_rn(xv, w4.x, g.x) + b4.x);
                hn.y = tanh_win(__fmaf_rn(xv, w4.y, g.y) + b4.y);
                hn.z = tanh_win(__fmaf_rn(xv, w4.z, g.z) + b4.z);
                hn.w = tanh_win(__fmaf_rn(xv, w4.w, g.w) + b4.w);
                *reinterpret_cast<float4*>(&hl[(rg * RPT + r) * HID + c0]) = hn;
            }
        }
        __syncthreads();   // h_{t+1} visible to all
    }

    // Epilogue: out = h_T @ W_ph + b_p (order-insensitive at bf16 threshold)
    if (tid < ROWS * NCLS) {
        const int r = tid / NCLS, k = tid - r * NCLS;
        float acc = bp[k];
        for (int j = 0; j < HID; ++j)
            acc = __fmaf_rn(hl[r * HID + j], W_ph[j * NCLS + k], acc);
        out[(size_t)(row0 + r) * NCLS + k] = acc;
    }
}

extern "C" void kernel_launch(void* const* d_in, const int* in_sizes, int n_in,
                              void* d_out, int out_size, void* d_ws, size_t ws_size,
                              hipStream_t stream) {
    const float* x    = (const float*)d_in[0];
    const float* W_hx = (const float*)d_in[1];
    const float* Whh  = (const float*)d_in[2];
    const float* W_ph = (const float*)d_in[3];
    const float* bh   = (const float*)d_in[4];
    const float* bp   = (const float*)d_in[5];
    float* out = (float*)d_out;

    rnn_win<<<2048 / ROWS, TPB, 0, stream>>>(x, W_hx, Whh, W_ph, bh, bp, out);
}

// Round 12
// 31792.642 us; speedup vs baseline: 1.1905x; 1.1905x over previous
//
#include <hip/hip_runtime.h>

// VanillaRNN — bit-exact specialized kernel, R12.
// Reference arithmetic (oracle winner v=75, verified bit-exact full-batch R6):
//   GEMM: per column, TWO k-panels {0..511},{512..1023}; each an independent
//         ascending-k FMA chain from 0; G = s0 + s1 (single commutative add).
//   z    = fma(x_t, w_c, G) + b_c
//   tanh = XLA FastTanh FMA-Horner, clamp ±7.99881172180175781, |x|<4e-4 -> x,
//          IEEE f32 divide.
// DO NOT reorder any FP op in the recurrence.
//
// Base = R10 (28.3 ms; W traffic-optimal: each W element read once per
// block-step; R11's row-split doubled L2 traffic -> 37.8 ms, reverted).
// R12 changes:
//  (1) explicit double-buffered W prefetch (load group g+1 while FMA group g)
//      -> L2 latency hidden under the 512-cyc FMA stream per group.
//  (2) finish split across panel-waves: p0 finishes rows 0-3, p1 rows 4-7
//      (g = s_own + s_other, commutative -> bit-identical); halves the tail.
// Shape: 256 blocks (1/CU) x 512 threads (2 waves/SIMD). Floors: FMA 14 ms,
// L2 W-traffic 512 GB ~ 15 ms.

#define SEQ   512
#define HID   1024
#define NCLS  10
#define TPB   512
#define ROWS  8
#define CLAMPV 7.99881172180175781f

__device__ __forceinline__ float tanh_win(float x) {
#pragma clang fp contract(off)
    float xc = fminf(fmaxf(x, -CLAMPV), CLAMPV);
    float x2 = xc * xc;
    float p = -2.76076847742355e-16f;
    p = __fmaf_rn(x2, p,  2.00018790482477e-13f);
    p = __fmaf_rn(x2, p, -8.60467152213735e-11f);
    p = __fmaf_rn(x2, p,  5.12229709037114e-08f);
    p = __fmaf_rn(x2, p,  1.48572235717979e-05f);
    p = __fmaf_rn(x2, p,  6.37261928875436e-04f);
    p = __fmaf_rn(x2, p,  4.89352455891786e-03f);
    p = xc * p;
    float q = 1.19825839466702e-06f;
    q = __fmaf_rn(x2, q,  1.18534705686654e-04f);
    q = __fmaf_rn(x2, q,  2.26843463243900e-03f);
    q = __fmaf_rn(x2, q,  4.89352518554385e-03f);
    float r = p / q;                      // IEEE f32 divide
    return (fabsf(x) < 0.0004f) ? x : r;  // passthrough on unclamped x
}

#define MAC4(hv, wv)                              \
    sv.x = __fmaf_rn((hv), (wv).x, sv.x);         \
    sv.y = __fmaf_rn((hv), (wv).y, sv.y);         \
    sv.z = __fmaf_rn((hv), (wv).z, sv.z);         \
    sv.w = __fmaf_rn((hv), (wv).w, sv.w);

__device__ __forceinline__ void loadgrp(float4 w[8], const float* __restrict__ Whh,
                                        unsigned off) {
    w[0] = *reinterpret_cast<const float4*>(Whh + off);
    w[1] = *reinterpret_cast<const float4*>(Whh + off + 1u * HID);
    w[2] = *reinterpret_cast<const float4*>(Whh + off + 2u * HID);
    w[3] = *reinterpret_cast<const float4*>(Whh + off + 3u * HID);
    w[4] = *reinterpret_cast<const float4*>(Whh + off + 4u * HID);
    w[5] = *reinterpret_cast<const float4*>(Whh + off + 5u * HID);
    w[6] = *reinterpret_cast<const float4*>(Whh + off + 6u * HID);
    w[7] = *reinterpret_cast<const float4*>(Whh + off + 7u * HID);
}

// FMA one j-group (8 k values) into all 8 rows' chains. Ascending k per
// (row,col) chain — FP sequence identical to R9/R10 (bit-exact).
__device__ __forceinline__ void fmagrp(float4 s[ROWS], const float4 w[8],
                                       const float* __restrict__ hl, int j) {
#pragma clang fp contract(off)
    #pragma unroll
    for (int r = 0; r < ROWS; ++r) {
        const float4 ha = *reinterpret_cast<const float4*>(&hl[r * HID + j]);
        const float4 hb = *reinterpret_cast<const float4*>(&hl[r * HID + j + 4]);
        float4 sv = s[r];
        MAC4(ha.x, w[0]); MAC4(ha.y, w[1]); MAC4(ha.z, w[2]); MAC4(ha.w, w[3]);
        MAC4(hb.x, w[4]); MAC4(hb.y, w[5]); MAC4(hb.z, w[6]); MAC4(hb.w, w[7]);
        s[r] = sv;
    }
}

__launch_bounds__(TPB, 2)
__global__ void rnn_win(const float* __restrict__ x, const float* __restrict__ W_hx,
                        const float* __restrict__ Whh, const float* __restrict__ W_ph,
                        const float* __restrict__ bh, const float* __restrict__ bp,
                        float* __restrict__ out) {
#pragma clang fp contract(off)
    __shared__ float hl[ROWS * HID];   // 32 KB  current hidden state
    __shared__ float xl[ROWS * SEQ];   // 16 KB  staged inputs
    __shared__ float sb[ROWS * HID];   // 32 KB  cross-panel subtotal exchange
    const int tid  = threadIdx.x;
    const int blk  = blockIdx.x;
    const int col  = tid & 255;        // colgroup id
    const int pp   = tid >> 8;         // panel id: 0 -> k 0..511, 1 -> k 512..1023
    const int c0   = col * 4;
    const int row0 = blk * ROWS;

    for (int i = tid; i < ROWS * SEQ; i += TPB) xl[i] = x[(size_t)row0 * SEQ + i];
    for (int i = tid; i < ROWS * HID; i += TPB) hl[i] = 0.0f;

    const float4 w4 = *reinterpret_cast<const float4*>(W_hx + c0);
    const float4 b4 = *reinterpret_cast<const float4*>(bh + c0);
    const unsigned off0 = (unsigned)(pp * 512 * HID + c0);
    // finish assignment: p0 -> rows 0..3, p1 -> rows 4..7
    const int frbase = pp * 4;         // rows this thread finishes
    const int prbase = 4 - frbase;     // rows this thread publishes (other half)
    __syncthreads();

    for (int t = 0; t < SEQ; ++t) {
        float4 s[ROWS];
        #pragma unroll
        for (int r = 0; r < ROWS; ++r) s[r] = float4{0.f, 0.f, 0.f, 0.f};

        // --- software-pipelined panel: 64 j-groups, double-buffered W ---
        {
            float4 wA[8], wB[8];
            unsigned off = off0;
            const int jb = pp * 512;
            loadgrp(wA, Whh, off);                       // group 0
            #pragma unroll 1
            for (int g = 0; g < 62; g += 2) {
                loadgrp(wB, Whh, off + 8u * HID);        // group g+1
                fmagrp(s, wA, hl, jb + g * 8);           // group g
                loadgrp(wA, Whh, off + 16u * HID);       // group g+2
                fmagrp(s, wB, hl, jb + g * 8 + 8);       // group g+1
                off += 16u * HID;
            }
            loadgrp(wB, Whh, off + 8u * HID);            // group 63
            fmagrp(s, wA, hl, jb + 62 * 8);              // group 62
            fmagrp(s, wB, hl, jb + 63 * 8);              // group 63
        }

        // publish the half the OTHER panel-group finishes
        #pragma unroll
        for (int r = 0; r < 4; ++r)
            *reinterpret_cast<float4*>(&sb[(prbase + r) * HID + c0]) = s[prbase + r];
        __syncthreads();   // h_t reads done; sb halves visible

        // finish own half: g = s_own + s_other (commutative -> bit-identical)
        #pragma unroll
        for (int r = 0; r < 4; ++r) {
            const int row = frbase + r;
            const float4 so = *reinterpret_cast<const float4*>(&sb[row * HID + c0]);
            const float xv = xl[row * SEQ + t];
            float4 g;
            g.x = s[row].x + so.x;
            g.y = s[row].y + so.y;
            g.z = s[row].z + so.z;
            g.w = s[row].w + so.w;
            float4 hn;
            hn.x = tanh_win(__fmaf_rn(xv, w4.x, g.x) + b4.x);
            hn.y = tanh_win(__fmaf_rn(xv, w4.y, g.y) + b4.y);
            hn.z = tanh_win(__fmaf_rn(xv, w4.z, g.z) + b4.z);
            hn.w = tanh_win(__fmaf_rn(xv, w4.w, g.w) + b4.w);
            *reinterpret_cast<float4*>(&hl[row * HID + c0]) = hn;
        }
        __syncthreads();   // h_{t+1} visible to all
    }

    // Epilogue: out = h_T @ W_ph + b_p (order-insensitive at bf16 threshold)
    if (tid < ROWS * NCLS) {
        const int r = tid / NCLS, k = tid - r * NCLS;
        float acc = bp[k];
        for (int j = 0; j < HID; ++j)
            acc = __fmaf_rn(hl[r * HID + j], W_ph[j * NCLS + k], acc);
        out[(size_t)(row0 + r) * NCLS + k] = acc;
    }
}

extern "C" void kernel_launch(void* const* d_in, const int* in_sizes, int n_in,
                              void* d_out, int out_size, void* d_ws, size_t ws_size,
                              hipStream_t stream) {
    const float* x    = (const float*)d_in[0];
    const float* W_hx = (const float*)d_in[1];
    const float* Whh  = (const float*)d_in[2];
    const float* W_ph = (const float*)d_in[3];
    const float* bh   = (const float*)d_in[4];
    const float* bp   = (const float*)d_in[5];
    float* out = (float*)d_out;

    rnn_win<<<2048 / ROWS, TPB, 0, stream>>>(x, W_hx, Whh, W_ph, bh, bp, out);
}

// Round 13
// 29467.114 us; speedup vs baseline: 1.2845x; 1.0789x over previous
//
#include <hip/hip_runtime.h>

// VanillaRNN — bit-exact specialized kernel, R13.
// Reference arithmetic (oracle winner v=75, verified bit-exact full-batch R6):
//   GEMM: per column, TWO k-panels {0..511},{512..1023}; each an independent
//         ascending-k FMA chain from 0; G = s0 + s1 (single commutative add).
//   z    = fma(x_t, w_c, G) + b_c
//   tanh = XLA FastTanh FMA-Horner, clamp ±7.99881172180175781, |x|<4e-4 -> x,
//          IEEE f32 divide.
// DO NOT reorder any FP op in the recurrence.
//
// R12 bug found via counters: FETCH 110MB -> 10.3GB = scratch spills from
// RUNTIME-indexed accumulator array (s[prbase+r] / s[frbase+r], rule #20).
// R13: identical schedule, but publish/finish are wave-uniform branches with
// COMPILE-TIME indices -> s[] stays in VGPRs. W double-buffer retained.
// Shape: 256 blocks (1/CU) x 512 threads (2 waves/SIMD).
// Floors: FMA 14 ms, L2 W-traffic 512 GB ~ 15 ms.

#define SEQ   512
#define HID   1024
#define NCLS  10
#define TPB   512
#define ROWS  8
#define CLAMPV 7.99881172180175781f

__device__ __forceinline__ float tanh_win(float x) {
#pragma clang fp contract(off)
    float xc = fminf(fmaxf(x, -CLAMPV), CLAMPV);
    float x2 = xc * xc;
    float p = -2.76076847742355e-16f;
    p = __fmaf_rn(x2, p,  2.00018790482477e-13f);
    p = __fmaf_rn(x2, p, -8.60467152213735e-11f);
    p = __fmaf_rn(x2, p,  5.12229709037114e-08f);
    p = __fmaf_rn(x2, p,  1.48572235717979e-05f);
    p = __fmaf_rn(x2, p,  6.37261928875436e-04f);
    p = __fmaf_rn(x2, p,  4.89352455891786e-03f);
    p = xc * p;
    float q = 1.19825839466702e-06f;
    q = __fmaf_rn(x2, q,  1.18534705686654e-04f);
    q = __fmaf_rn(x2, q,  2.26843463243900e-03f);
    q = __fmaf_rn(x2, q,  4.89352518554385e-03f);
    float r = p / q;                      // IEEE f32 divide
    return (fabsf(x) < 0.0004f) ? x : r;  // passthrough on unclamped x
}

#define MAC4(hv, wv)                              \
    sv.x = __fmaf_rn((hv), (wv).x, sv.x);         \
    sv.y = __fmaf_rn((hv), (wv).y, sv.y);         \
    sv.z = __fmaf_rn((hv), (wv).z, sv.z);         \
    sv.w = __fmaf_rn((hv), (wv).w, sv.w);

__device__ __forceinline__ void loadgrp(float4 w[8], const float* __restrict__ Whh,
                                        unsigned off) {
    w[0] = *reinterpret_cast<const float4*>(Whh + off);
    w[1] = *reinterpret_cast<const float4*>(Whh + off + 1u * HID);
    w[2] = *reinterpret_cast<const float4*>(Whh + off + 2u * HID);
    w[3] = *reinterpret_cast<const float4*>(Whh + off + 3u * HID);
    w[4] = *reinterpret_cast<const float4*>(Whh + off + 4u * HID);
    w[5] = *reinterpret_cast<const float4*>(Whh + off + 5u * HID);
    w[6] = *reinterpret_cast<const float4*>(Whh + off + 6u * HID);
    w[7] = *reinterpret_cast<const float4*>(Whh + off + 7u * HID);
}

// FMA one j-group (8 k values) into all 8 rows' chains. Ascending k per
// (row,col) chain — FP sequence identical to R9/R10 (bit-exact).
__device__ __forceinline__ void fmagrp(float4 s[ROWS], const float4 w[8],
                                       const float* __restrict__ hl, int j) {
#pragma clang fp contract(off)
    #pragma unroll
    for (int r = 0; r < ROWS; ++r) {
        const float4 ha = *reinterpret_cast<const float4*>(&hl[r * HID + j]);
        const float4 hb = *reinterpret_cast<const float4*>(&hl[r * HID + j + 4]);
        float4 sv = s[r];
        MAC4(ha.x, w[0]); MAC4(ha.y, w[1]); MAC4(ha.z, w[2]); MAC4(ha.w, w[3]);
        MAC4(hb.x, w[4]); MAC4(hb.y, w[5]); MAC4(hb.z, w[6]); MAC4(hb.w, w[7]);
        s[r] = sv;
    }
}

// Finish one row: g = s_own + s_other; z = fma(x,w,g)+b; h = tanh(z).
#define FINISH_ROW(ROW)                                                        \
    {                                                                          \
        const float4 so = *reinterpret_cast<const float4*>(&sb[(ROW) * HID + c0]); \
        const float xv = xl[(ROW) * SEQ + t];                                  \
        float4 g;                                                              \
        g.x = s[ROW].x + so.x;                                                 \
        g.y = s[ROW].y + so.y;                                                 \
        g.z = s[ROW].z + so.z;                                                 \
        g.w = s[ROW].w + so.w;                                                 \
        float4 hn;                                                             \
        hn.x = tanh_win(__fmaf_rn(xv, w4.x, g.x) + b4.x);                      \
        hn.y = tanh_win(__fmaf_rn(xv, w4.y, g.y) + b4.y);                      \
        hn.z = tanh_win(__fmaf_rn(xv, w4.z, g.z) + b4.z);                      \
        hn.w = tanh_win(__fmaf_rn(xv, w4.w, g.w) + b4.w);                      \
        *reinterpret_cast<float4*>(&hl[(ROW) * HID + c0]) = hn;                \
    }

__launch_bounds__(TPB, 2)
__global__ void rnn_win(const float* __restrict__ x, const float* __restrict__ W_hx,
                        const float* __restrict__ Whh, const float* __restrict__ W_ph,
                        const float* __restrict__ bh, const float* __restrict__ bp,
                        float* __restrict__ out) {
#pragma clang fp contract(off)
    __shared__ float hl[ROWS * HID];   // 32 KB  current hidden state
    __shared__ float xl[ROWS * SEQ];   // 16 KB  staged inputs
    __shared__ float sb[ROWS * HID];   // 32 KB  cross-panel subtotal exchange
    const int tid  = threadIdx.x;
    const int blk  = blockIdx.x;
    const int col  = tid & 255;        // colgroup id
    const int pp   = tid >> 8;         // panel id: 0 -> k 0..511, 1 -> k 512..1023
    const int c0   = col * 4;
    const int row0 = blk * ROWS;

    for (int i = tid; i < ROWS * SEQ; i += TPB) xl[i] = x[(size_t)row0 * SEQ + i];
    for (int i = tid; i < ROWS * HID; i += TPB) hl[i] = 0.0f;

    const float4 w4 = *reinterpret_cast<const float4*>(W_hx + c0);
    const float4 b4 = *reinterpret_cast<const float4*>(bh + c0);
    const unsigned off0 = (unsigned)(pp * 512 * HID + c0);
    __syncthreads();

    for (int t = 0; t < SEQ; ++t) {
        float4 s[ROWS];
        #pragma unroll
        for (int r = 0; r < ROWS; ++r) s[r] = float4{0.f, 0.f, 0.f, 0.f};

        // --- software-pipelined panel: 64 j-groups, double-buffered W ---
        {
            float4 wA[8], wB[8];
            unsigned off = off0;
            const int jb = pp * 512;
            loadgrp(wA, Whh, off);                       // group 0
            #pragma unroll 1
            for (int g = 0; g < 62; g += 2) {
                loadgrp(wB, Whh, off + 8u * HID);        // group g+1
                fmagrp(s, wA, hl, jb + g * 8);           // group g
                loadgrp(wA, Whh, off + 16u * HID);       // group g+2
                fmagrp(s, wB, hl, jb + g * 8 + 8);       // group g+1
                off += 16u * HID;
            }
            loadgrp(wB, Whh, off + 8u * HID);            // group 63
            fmagrp(s, wA, hl, jb + 62 * 8);              // group 62
            fmagrp(s, wB, hl, jb + 63 * 8);              // group 63
        }

        // publish the half the OTHER panel-group finishes (static indices!)
        if (pp == 0) {
            *reinterpret_cast<float4*>(&sb[4 * HID + c0]) = s[4];
            *reinterpret_cast<float4*>(&sb[5 * HID + c0]) = s[5];
            *reinterpret_cast<float4*>(&sb[6 * HID + c0]) = s[6];
            *reinterpret_cast<float4*>(&sb[7 * HID + c0]) = s[7];
        } else {
            *reinterpret_cast<float4*>(&sb[0 * HID + c0]) = s[0];
            *reinterpret_cast<float4*>(&sb[1 * HID + c0]) = s[1];
            *reinterpret_cast<float4*>(&sb[2 * HID + c0]) = s[2];
            *reinterpret_cast<float4*>(&sb[3 * HID + c0]) = s[3];
        }
        __syncthreads();   // h_t reads done; sb halves visible

        // finish own half (static indices; g = s_own + s_other, commutative)
        if (pp == 0) {
            FINISH_ROW(0); FINISH_ROW(1); FINISH_ROW(2); FINISH_ROW(3);
        } else {
            FINISH_ROW(4); FINISH_ROW(5); FINISH_ROW(6); FINISH_ROW(7);
        }
        __syncthreads();   // h_{t+1} visible to all
    }

    // Epilogue: out = h_T @ W_ph + b_p (order-insensitive at bf16 threshold)
    if (tid < ROWS * NCLS) {
        const int r = tid / NCLS, k = tid - r * NCLS;
        float acc = bp[k];
        for (int j = 0; j < HID; ++j)
            acc = __fmaf_rn(hl[r * HID + j], W_ph[j * NCLS + k], acc);
        out[(size_t)(row0 + r) * NCLS + k] = acc;
    }
}

extern "C" void kernel_launch(void* const* d_in, const int* in_sizes, int n_in,
                              void* d_out, int out_size, void* d_ws, size_t ws_size,
                              hipStream_t stream) {
    const float* x    = (const float*)d_in[0];
    const float* W_hx = (const float*)d_in[1];
    const float* Whh  = (const float*)d_in[2];
    const float* W_ph = (const float*)d_in[3];
    const float* bh   = (const float*)d_in[4];
    const float* bp   = (const float*)d_in[5];
    float* out = (float*)d_out;

    rnn_win<<<2048 / ROWS, TPB, 0, stream>>>(x, W_hx, Whh, W_ph, bh, bp, out);
}

// Round 14
// 28421.057 us; speedup vs baseline: 1.3318x; 1.0368x over previous
//
#include <hip/hip_runtime.h>

// VanillaRNN — bit-exact specialized kernel, R14.
// Reference arithmetic (oracle winner v=75, verified bit-exact full-batch R6):
//   GEMM: per column, TWO k-panels {0..511},{512..1023}; each an independent
//         ascending-k FMA chain from 0; G = s0 + s1 (single commutative add).
//   z    = fma(x_t, w_c, G) + b_c
//   tanh = XLA FastTanh FMA-Horner, clamp ±7.99881172180175781, |x|<4e-4 -> x,
//          IEEE f32 divide.
// DO NOT reorder any FP op in the recurrence.
//
// R13 counters: FETCH still 15.2 GB (scratch reads + L2 pollution evicting
// the 4MB W_hh) from the too-fat wA[8]/wB[8] prefetch. R14:
//  (1) prefetch depth 4 (wA[4]/wB[4], j-groups of 4) -> ~32 buffer VGPRs,
//      no scratch;
//  (2) cross-barrier W prefetch: group 0 of step t+1 loads before the
//      publish/barrier (W is h-independent) -> step-start latency hidden;
//  (3) launch_bounds(512,1): let VGPRs float (occupancy is LDS-bound at
//      1 block/CU anyway).
// Shape: 256 blocks x 512 threads (2 waves/SIMD), W traffic-optimal.
// Floors: FMA 14 ms, L2 W-traffic 512 GB ~ 15 ms.

#define SEQ   512
#define HID   1024
#define NCLS  10
#define TPB   512
#define ROWS  8
#define CLAMPV 7.99881172180175781f

__device__ __forceinline__ float tanh_win(float x) {
#pragma clang fp contract(off)
    float xc = fminf(fmaxf(x, -CLAMPV), CLAMPV);
    float x2 = xc * xc;
    float p = -2.76076847742355e-16f;
    p = __fmaf_rn(x2, p,  2.00018790482477e-13f);
    p = __fmaf_rn(x2, p, -8.60467152213735e-11f);
    p = __fmaf_rn(x2, p,  5.12229709037114e-08f);
    p = __fmaf_rn(x2, p,  1.48572235717979e-05f);
    p = __fmaf_rn(x2, p,  6.37261928875436e-04f);
    p = __fmaf_rn(x2, p,  4.89352455891786e-03f);
    p = xc * p;
    float q = 1.19825839466702e-06f;
    q = __fmaf_rn(x2, q,  1.18534705686654e-04f);
    q = __fmaf_rn(x2, q,  2.26843463243900e-03f);
    q = __fmaf_rn(x2, q,  4.89352518554385e-03f);
    float r = p / q;                      // IEEE f32 divide
    return (fabsf(x) < 0.0004f) ? x : r;  // passthrough on unclamped x
}

#define MAC4(hv, wv)                              \
    sv.x = __fmaf_rn((hv), (wv).x, sv.x);         \
    sv.y = __fmaf_rn((hv), (wv).y, sv.y);         \
    sv.z = __fmaf_rn((hv), (wv).z, sv.z);         \
    sv.w = __fmaf_rn((hv), (wv).w, sv.w);

// Load 4 consecutive W rows (k..k+3) at column group c0 (via byte offset off).
__device__ __forceinline__ void loadg4(float4 w[4], const float* __restrict__ Whh,
                                       unsigned off) {
    w[0] = *reinterpret_cast<const float4*>(Whh + off);
    w[1] = *reinterpret_cast<const float4*>(Whh + off + 1u * HID);
    w[2] = *reinterpret_cast<const float4*>(Whh + off + 2u * HID);
    w[3] = *reinterpret_cast<const float4*>(Whh + off + 3u * HID);
}

// FMA one j-group (4 k values) into all 8 rows' chains. Ascending k per
// (row,col) chain — FP sequence identical to R9/R10/R13 (bit-exact).
__device__ __forceinline__ void fmag4(float4 s[ROWS], const float4 w[4],
                                      const float* __restrict__ hl, int j) {
#pragma clang fp contract(off)
    #pragma unroll
    for (int r = 0; r < ROWS; ++r) {
        const float4 ha = *reinterpret_cast<const float4*>(&hl[r * HID + j]);
        float4 sv = s[r];
        MAC4(ha.x, w[0]); MAC4(ha.y, w[1]); MAC4(ha.z, w[2]); MAC4(ha.w, w[3]);
        s[r] = sv;
    }
}

// Finish one row: g = s_own + s_other; z = fma(x,w,g)+b; h = tanh(z).
#define FINISH_ROW(ROW)                                                        \
    {                                                                          \
        const float4 so = *reinterpret_cast<const float4*>(&sb[(ROW) * HID + c0]); \
        const float xv = xl[(ROW) * SEQ + t];                                  \
        float4 g;                                                              \
        g.x = s[ROW].x + so.x;                                                 \
        g.y = s[ROW].y + so.y;                                                 \
        g.z = s[ROW].z + so.z;                                                 \
        g.w = s[ROW].w + so.w;                                                 \
        float4 hn;                                                             \
        hn.x = tanh_win(__fmaf_rn(xv, w4.x, g.x) + b4.x);                      \
        hn.y = tanh_win(__fmaf_rn(xv, w4.y, g.y) + b4.y);                      \
        hn.z = tanh_win(__fmaf_rn(xv, w4.z, g.z) + b4.z);                      \
        hn.w = tanh_win(__fmaf_rn(xv, w4.w, g.w) + b4.w);                      \
        *reinterpret_cast<float4*>(&hl[(ROW) * HID + c0]) = hn;                \
    }

__launch_bounds__(TPB, 1)
__global__ void rnn_win(const float* __restrict__ x, const float* __restrict__ W_hx,
                        const float* __restrict__ Whh, const float* __restrict__ W_ph,
                        const float* __restrict__ bh, const float* __restrict__ bp,
                        float* __restrict__ out) {
#pragma clang fp contract(off)
    __shared__ float hl[ROWS * HID];   // 32 KB  current hidden state
    __shared__ float xl[ROWS * SEQ];   // 16 KB  staged inputs
    __shared__ float sb[ROWS * HID];   // 32 KB  cross-panel subtotal exchange
    const int tid  = threadIdx.x;
    const int blk  = blockIdx.x;
    const int col  = tid & 255;        // colgroup id
    const int pp   = tid >> 8;         // panel id: 0 -> k 0..511, 1 -> k 512..1023
    const int c0   = col * 4;
    const int row0 = blk * ROWS;

    for (int i = tid; i < ROWS * SEQ; i += TPB) xl[i] = x[(size_t)row0 * SEQ + i];
    for (int i = tid; i < ROWS * HID; i += TPB) hl[i] = 0.0f;

    const float4 w4 = *reinterpret_cast<const float4*>(W_hx + c0);
    const float4 b4 = *reinterpret_cast<const float4*>(bh + c0);
    const unsigned off0 = (unsigned)(pp * 512 * HID + c0);
    const int jb = pp * 512;
    __syncthreads();

    float4 wA[4], wB[4];
    loadg4(wA, Whh, off0);             // group 0 of step 0

    for (int t = 0; t < SEQ; ++t) {
        float4 s[ROWS];
        #pragma unroll
        for (int r = 0; r < ROWS; ++r) s[r] = float4{0.f, 0.f, 0.f, 0.f};

        // --- software-pipelined panel: 128 j-groups of 4, double-buffered ---
        unsigned off = off0;
        #pragma unroll 1
        for (int g = 0; g < 126; g += 2) {
            loadg4(wB, Whh, off + 4u * HID);         // group g+1
            fmag4(s, wA, hl, jb + g * 4);            // group g
            loadg4(wA, Whh, off + 8u * HID);         // group g+2
            fmag4(s, wB, hl, jb + (g + 1) * 4);      // group g+1
            off += 8u * HID;
        }
        loadg4(wB, Whh, off + 4u * HID);             // group 127
        fmag4(s, wA, hl, jb + 126 * 4);              // group 126
        loadg4(wA, Whh, off0);                       // PREFETCH group 0 of t+1
        fmag4(s, wB, hl, jb + 127 * 4);              // group 127

        // publish the half the OTHER panel-group finishes (static indices)
        if (pp == 0) {
            *reinterpret_cast<float4*>(&sb[4 * HID + c0]) = s[4];
            *reinterpret_cast<float4*>(&sb[5 * HID + c0]) = s[5];
            *reinterpret_cast<float4*>(&sb[6 * HID + c0]) = s[6];
            *reinterpret_cast<float4*>(&sb[7 * HID + c0]) = s[7];
        } else {
            *reinterpret_cast<float4*>(&sb[0 * HID + c0]) = s[0];
            *reinterpret_cast<float4*>(&sb[1 * HID + c0]) = s[1];
            *reinterpret_cast<float4*>(&sb[2 * HID + c0]) = s[2];
            *reinterpret_cast<float4*>(&sb[3 * HID + c0]) = s[3];
        }
        __syncthreads();   // h_t reads done; sb halves visible

        // finish own half (static indices; g = s_own + s_other, commutative)
        if (pp == 0) {
            FINISH_ROW(0); FINISH_ROW(1); FINISH_ROW(2); FINISH_ROW(3);
        } else {
            FINISH_ROW(4); FINISH_ROW(5); FINISH_ROW(6); FINISH_ROW(7);
        }
        __syncthreads();   // h_{t+1} visible to all
    }

    // Epilogue: out = h_T @ W_ph + b_p (order-insensitive at bf16 threshold)
    if (tid < ROWS * NCLS) {
        const int r = tid / NCLS, k = tid - r * NCLS;
        float acc = bp[k];
        for (int j = 0; j < HID; ++j)
            acc = __fmaf_rn(hl[r * HID + j], W_ph[j * NCLS + k], acc);
        out[(size_t)(row0 + r) * NCLS + k] = acc;
    }
}

extern "C" void kernel_launch(void* const* d_in, const int* in_sizes, int n_in,
                              void* d_out, int out_size, void* d_ws, size_t ws_size,
                              hipStream_t stream) {
    const float* x    = (const float*)d_in[0];
    const float* W_hx = (const float*)d_in[1];
    const float* Whh  = (const float*)d_in[2];
    const float* W_ph = (const float*)d_in[3];
    const float* bh   = (const float*)d_in[4];
    const float* bp   = (const float*)d_in[5];
    float* out = (float*)d_out;

    rnn_win<<<2048 / ROWS, TPB, 0, stream>>>(x, W_hx, Whh, W_ph, bh, bp, out);
}

// Round 15
// 27529.099 us; speedup vs baseline: 1.3749x; 1.0324x over previous
//
#include <hip/hip_runtime.h>

// VanillaRNN — bit-exact specialized kernel, R15.
// Reference arithmetic (oracle winner v=75, verified bit-exact full-batch R6):
//   GEMM: per column, TWO k-panels {0..511},{512..1023}; each an independent
//         ascending-k FMA chain from 0; G = s0 + s1 (single commutative add).
//   z    = fma(x_t, w_c, G) + b_c
//   tanh = XLA FastTanh FMA-Horner, clamp ±7.99881172180175781, |x|<4e-4 -> x,
//          IEEE f32 divide.
// DO NOT reorder any FP op in the recurrence.
//
// R14 accounting: 49% FMA, 27% aux VALU (addressing/movs), 24% stall.
// R15: (1) uniform-base W addressing (SALU-advanced wub + compile-time row
// offsets), (2) immediate-offset ds_reads (one hj+=12 per 3 groups),
// (3) triple-buffered W A/B/C with 2-group (~512 cyc) lookahead covering L2
// latency, (4) cross-step prefetch. FP chains bit-identical.
// Shape: 256 blocks x 512 threads (2 waves/SIMD), W traffic-optimal.
// Floors: FMA 14 ms, L2 W-traffic 512 GB ~ 15 ms.

#define SEQ   512
#define HID   1024
#define NCLS  10
#define TPB   512
#define ROWS  8
#define CLAMPV 7.99881172180175781f

__device__ __forceinline__ float tanh_win(float x) {
#pragma clang fp contract(off)
    float xc = fminf(fmaxf(x, -CLAMPV), CLAMPV);
    float x2 = xc * xc;
    float p = -2.76076847742355e-16f;
    p = __fmaf_rn(x2, p,  2.00018790482477e-13f);
    p = __fmaf_rn(x2, p, -8.60467152213735e-11f);
    p = __fmaf_rn(x2, p,  5.12229709037114e-08f);
    p = __fmaf_rn(x2, p,  1.48572235717979e-05f);
    p = __fmaf_rn(x2, p,  6.37261928875436e-04f);
    p = __fmaf_rn(x2, p,  4.89352455891786e-03f);
    p = xc * p;
    float q = 1.19825839466702e-06f;
    q = __fmaf_rn(x2, q,  1.18534705686654e-04f);
    q = __fmaf_rn(x2, q,  2.26843463243900e-03f);
    q = __fmaf_rn(x2, q,  4.89352518554385e-03f);
    float r = p / q;                      // IEEE f32 divide
    return (fabsf(x) < 0.0004f) ? x : r;  // passthrough on unclamped x
}

#define MAC4(hv, wv)                              \
    sv.x = __fmaf_rn((hv), (wv).x, sv.x);         \
    sv.y = __fmaf_rn((hv), (wv).y, sv.y);         \
    sv.z = __fmaf_rn((hv), (wv).z, sv.z);         \
    sv.w = __fmaf_rn((hv), (wv).w, sv.w);

// Load one 4-k-row W group at compile-time row offset R0 from uniform ptr P.
#define LOADG(B0_, B1_, B2_, B3_, P, R0)                                       \
    B0_ = *reinterpret_cast<const float4*>((P) + ((R0)    ) * HID + c0);       \
    B1_ = *reinterpret_cast<const float4*>((P) + ((R0) + 1) * HID + c0);       \
    B2_ = *reinterpret_cast<const float4*>((P) + ((R0) + 2) * HID + c0);       \
    B3_ = *reinterpret_cast<const float4*>((P) + ((R0) + 3) * HID + c0);

// FMA one 4-k group (weights W0..W3) into all 8 rows' chains; h read at
// iter-local compile-time offset J from hj. Ascending k per (row,col) chain
// — FP sequence identical to R9/R10/R14 (bit-exact).
#define FMAG(W0_, W1_, W2_, W3_, J)                                            \
    {                                                                          \
        _Pragma("unroll")                                                      \
        for (int r = 0; r < ROWS; ++r) {                                       \
            const float4 ha =                                                  \
                *reinterpret_cast<const float4*>(hj + r * HID + (J));          \
            float4 sv = s[r];                                                  \
            MAC4(ha.x, W0_); MAC4(ha.y, W1_);                                  \
            MAC4(ha.z, W2_); MAC4(ha.w, W3_);                                  \
            s[r] = sv;                                                         \
        }                                                                      \
    }

// Finish one row: g = s_own + s_other; z = fma(x,w,g)+b; h = tanh(z).
#define FINISH_ROW(ROW)                                                        \
    {                                                                          \
        const float4 so = *reinterpret_cast<const float4*>(&sb[(ROW) * HID + c0]); \
        const float xv = xl[(ROW) * SEQ + t];                                  \
        float4 g;                                                              \
        g.x = s[ROW].x + so.x;                                                 \
        g.y = s[ROW].y + so.y;                                                 \
        g.z = s[ROW].z + so.z;                                                 \
        g.w = s[ROW].w + so.w;                                                 \
        float4 hn;                                                             \
        hn.x = tanh_win(__fmaf_rn(xv, w4.x, g.x) + b4.x);                      \
        hn.y = tanh_win(__fmaf_rn(xv, w4.y, g.y) + b4.y);                      \
        hn.z = tanh_win(__fmaf_rn(xv, w4.z, g.z) + b4.z);                      \
        hn.w = tanh_win(__fmaf_rn(xv, w4.w, g.w) + b4.w);                      \
        *reinterpret_cast<float4*>(&hl[(ROW) * HID + c0]) = hn;                \
    }

__launch_bounds__(TPB, 1)
__global__ void rnn_win(const float* __restrict__ x, const float* __restrict__ W_hx,
                        const float* __restrict__ Whh, const float* __restrict__ W_ph,
                        const float* __restrict__ bh, const float* __restrict__ bp,
                        float* __restrict__ out) {
#pragma clang fp contract(off)
    __shared__ float hl[ROWS * HID];   // 32 KB  current hidden state
    __shared__ float xl[ROWS * SEQ];   // 16 KB  staged inputs
    __shared__ float sb[ROWS * HID];   // 32 KB  cross-panel subtotal exchange
    const int tid  = threadIdx.x;
    const int blk  = blockIdx.x;
    const int col  = tid & 255;        // colgroup id
    const int pp   = tid >> 8;         // panel id: 0 -> k 0..511, 1 -> k 512..1023
    const int c0   = col * 4;
    const int row0 = blk * ROWS;

    for (int i = tid; i < ROWS * SEQ; i += TPB) xl[i] = x[(size_t)row0 * SEQ + i];
    for (int i = tid; i < ROWS * HID; i += TPB) hl[i] = 0.0f;

    const float4 w4 = *reinterpret_cast<const float4*>(W_hx + c0);
    const float4 b4 = *reinterpret_cast<const float4*>(bh + c0);
    const float* wub0 = Whh + (size_t)(pp * 512) * HID;   // uniform panel base
    __syncthreads();

    float4 A0, A1, A2, A3, B0, B1, B2, B3, C0, C1, C2, C3;
    LOADG(C0, C1, C2, C3, wub0, 0);    // group 0 of step 0

    for (int t = 0; t < SEQ; ++t) {
        // step prologue: A <- C (group 0, loaded last step), issue group 1
        A0 = C0; A1 = C1; A2 = C2; A3 = C3;
        LOADG(B0, B1, B2, B3, wub0, 4);

        float4 s[ROWS];
        #pragma unroll
        for (int r = 0; r < ROWS; ++r) s[r] = float4{0.f, 0.f, 0.f, 0.f};

        const float* wub = wub0;           // uniform, SALU-advanced
        const float* hj  = &hl[pp * 512];  // LDS base, one v_add per iter
        // 42 iters x 3 groups: fma 3i,3i+1,3i+2; load 3i+2,3i+3,3i+4.
        // Lookahead = 2 groups (~512 FMA-cyc) > L2 latency.
        #pragma unroll 1
        for (int i = 0; i < 42; ++i) {
            LOADG(C0, C1, C2, C3, wub, 8);     // group 3i+2
            FMAG(A0, A1, A2, A3, 0);           // group 3i
            LOADG(A0, A1, A2, A3, wub, 12);    // group 3i+3
            FMAG(B0, B1, B2, B3, 4);           // group 3i+1
            LOADG(B0, B1, B2, B3, wub, 16);    // group 3i+4
            FMAG(C0, C1, C2, C3, 8);           // group 3i+2
            wub += 12 * HID;
            hj  += 12;
        }
        // tail: groups 126 (in A), 127 (in B); prefetch group 0 of t+1 into C
        LOADG(C0, C1, C2, C3, wub0, 0);
        FMAG(A0, A1, A2, A3, 0);               // group 126 (j=504..507)
        FMAG(B0, B1, B2, B3, 4);               // group 127 (j=508..511)

        // publish the half the OTHER panel-group finishes (static indices)
        if (pp == 0) {
            *reinterpret_cast<float4*>(&sb[4 * HID + c0]) = s[4];
            *reinterpret_cast<float4*>(&sb[5 * HID + c0]) = s[5];
            *reinterpret_cast<float4*>(&sb[6 * HID + c0]) = s[6];
            *reinterpret_cast<float4*>(&sb[7 * HID + c0]) = s[7];
        } else {
            *reinterpret_cast<float4*>(&sb[0 * HID + c0]) = s[0];
            *reinterpret_cast<float4*>(&sb[1 * HID + c0]) = s[1];
            *reinterpret_cast<float4*>(&sb[2 * HID + c0]) = s[2];
            *reinterpret_cast<float4*>(&sb[3 * HID + c0]) = s[3];
        }
        __syncthreads();   // h_t reads done; sb halves visible

        // finish own half (static indices; g = s_own + s_other, commutative)
        if (pp == 0) {
            FINISH_ROW(0); FINISH_ROW(1); FINISH_ROW(2); FINISH_ROW(3);
        } else {
            FINISH_ROW(4); FINISH_ROW(5); FINISH_ROW(6); FINISH_ROW(7);
        }
        __syncthreads();   // h_{t+1} visible to all
    }

    // Epilogue: out = h_T @ W_ph + b_p (order-insensitive at bf16 threshold)
    if (tid < ROWS * NCLS) {
        const int r = tid / NCLS, k = tid - r * NCLS;
        float acc = bp[k];
        for (int j = 0; j < HID; ++j)
            acc = __fmaf_rn(hl[r * HID + j], W_ph[j * NCLS + k], acc);
        out[(size_t)(row0 + r) * NCLS + k] = acc;
    }
}

extern "C" void kernel_launch(void* const* d_in, const int* in_sizes, int n_in,
                              void* d_out, int out_size, void* d_ws, size_t ws_size,
                              hipStream_t stream) {
    const float* x    = (const float*)d_in[0];
    const float* W_hx = (const float*)d_in[1];
    const float* Whh  = (const float*)d_in[2];
    const float* W_ph = (const float*)d_in[3];
    const float* bh   = (const float*)d_in[4];
    const float* bp   = (const float*)d_in[5];
    float* out = (float*)d_out;

    rnn_win<<<2048 / ROWS, TPB, 0, stream>>>(x, W_hx, Whh, W_ph, bh, bp, out);
}